// Round 1
// baseline (1130.389 us; speedup 1.0000x reference)
//
#include <hip/hip_runtime.h>

// ---------- constants ----------
// B=8, Q=100, HW=16384, D=256, H=8, hd=32, FF=2048
#define SCALE 0.17677669529663687f  // 1/sqrt(32)

typedef __attribute__((ext_vector_type(8))) short frag8;   // 8 bf16 (A/B operand)
typedef __attribute__((ext_vector_type(4))) float facc4;   // 4 f32 (C/D)

#define MFMA16(a, b, c) __builtin_amdgcn_mfma_f32_16x16x32_bf16((a), (b), (c), 0, 0, 0)

__device__ __forceinline__ unsigned short f2b(float f) {
  union { float f; unsigned u; } v; v.f = f;
  return (unsigned short)((v.u + 0x7fffu + ((v.u >> 16) & 1u)) >> 16);
}
__device__ __forceinline__ float b2f(unsigned short h) {
  union { unsigned u; float f; } v; v.u = ((unsigned)h) << 16;
  return v.f;
}

// ---------- generic small fp32 GEMM: C[M,N] = A[M,K] @ W[N,K]^T + bias, opt relu ----------
template <int RELU>
__global__ __launch_bounds__(256) void small_gemm(const float* __restrict__ A,
                                                  const float* __restrict__ W,
                                                  const float* __restrict__ bias,
                                                  float* __restrict__ C,
                                                  int M, int N, int K) {
  __shared__ float As[64][20];
  __shared__ float Bs[64][20];
  const int t = threadIdx.x;
  const int mb = blockIdx.x, nb = blockIdx.y;
  const int tm = t >> 4, tn = t & 15;
  const int r = t >> 2, c4 = (t & 3) * 4;
  float acc[4][4] = {};
  for (int k0 = 0; k0 < K; k0 += 16) {
    int gr = mb * 64 + r;
    float4 av;
    if (gr < M) av = *(const float4*)(A + (size_t)gr * K + k0 + c4);
    else av = make_float4(0.f, 0.f, 0.f, 0.f);
    float4 wv = *(const float4*)(W + (size_t)(nb * 64 + r) * K + k0 + c4);
    *(float4*)&As[r][c4] = av;
    *(float4*)&Bs[r][c4] = wv;
    __syncthreads();
#pragma unroll
    for (int k4 = 0; k4 < 4; ++k4) {
      float4 a[4], bq[4];
#pragma unroll
      for (int i = 0; i < 4; ++i) a[i] = *(const float4*)&As[tm * 4 + i][k4 * 4];
#pragma unroll
      for (int j = 0; j < 4; ++j) bq[j] = *(const float4*)&Bs[tn * 4 + j][k4 * 4];
#pragma unroll
      for (int i = 0; i < 4; ++i)
#pragma unroll
        for (int j = 0; j < 4; ++j)
          acc[i][j] += a[i].x * bq[j].x + a[i].y * bq[j].y + a[i].z * bq[j].z + a[i].w * bq[j].w;
    }
    __syncthreads();
  }
#pragma unroll
  for (int i = 0; i < 4; ++i) {
    int row = mb * 64 + tm * 4 + i;
    if (row >= M) continue;
#pragma unroll
    for (int j = 0; j < 4; ++j) {
      int col = nb * 64 + tn * 4 + j;
      float v = acc[i][j] + bias[col];
      if (RELU) v = fmaxf(v, 0.f);
      C[(size_t)row * N + col] = v;
    }
  }
}

// ---------- residual + LayerNorm over 256 cols, one block per row ----------
__global__ __launch_bounds__(256) void res_ln(const float* __restrict__ y,
                                              const float* __restrict__ resid,
                                              const float* __restrict__ g,
                                              const float* __restrict__ bv,
                                              float* __restrict__ out) {
  const int r = blockIdx.x, t = threadIdx.x;
  float v = y[(size_t)r * 256 + t] + resid[(size_t)r * 256 + t];
  __shared__ float red[8];
  float s1 = v, s2 = v * v;
#pragma unroll
  for (int off = 1; off < 64; off <<= 1) {
    s1 += __shfl_xor(s1, off, 64);
    s2 += __shfl_xor(s2, off, 64);
  }
  if ((t & 63) == 0) { red[t >> 6] = s1; red[4 + (t >> 6)] = s2; }
  __syncthreads();
  float S1 = red[0] + red[1] + red[2] + red[3];
  float S2 = red[4] + red[5] + red[6] + red[7];
  float mu = S1 * (1.f / 256.f);
  float var = S2 * (1.f / 256.f) - mu * mu;
  float inv = rsqrtf(var + 1e-5f);
  out[(size_t)r * 256 + t] = (v - mu) * inv * g[t] + bv[t];
}

// ---------- self-attention (S=100, no mask), one wave per (b,h,q) row ----------
__global__ __launch_bounds__(256) void self_attn(const float* __restrict__ qkv,
                                                 float* __restrict__ out) {
  const int wid = blockIdx.x * 4 + (threadIdx.x >> 6);  // 0..6399
  const int lane = threadIdx.x & 63;
  const int bh = wid / 100, q = wid - bh * 100;
  const int b = bh >> 3, h = bh & 7;
  float4 qv[8];
  {
    const float4* qr = (const float4*)(qkv + (size_t)(b * 100 + q) * 768 + h * 32);
#pragma unroll
    for (int i = 0; i < 8; ++i) {
      float4 x = qr[i];
      qv[i] = make_float4(x.x * SCALE, x.y * SCALE, x.z * SCALE, x.w * SCALE);
    }
  }
  float l = 0.f;
  float4 O[8] = {};
  for (int k0 = 0; k0 < 128; k0 += 64) {
    int k = k0 + lane;
    int kc = (k < 100) ? k : 0;
    const float4* kr = (const float4*)(qkv + (size_t)(b * 100 + kc) * 768 + 256 + h * 32);
    float s = 0.f;
#pragma unroll
    for (int i = 0; i < 8; ++i) {
      float4 kx = kr[i];
      s += qv[i].x * kx.x + qv[i].y * kx.y + qv[i].z * kx.z + qv[i].w * kx.w;
    }
    float p = (k < 100) ? __expf(s) : 0.f;
    l += p;
    const float4* vr = (const float4*)(qkv + (size_t)(b * 100 + kc) * 768 + 512 + h * 32);
#pragma unroll
    for (int i = 0; i < 8; ++i) {
      float4 vx = vr[i];
      O[i].x += p * vx.x; O[i].y += p * vx.y; O[i].z += p * vx.z; O[i].w += p * vx.w;
    }
  }
#pragma unroll
  for (int off = 1; off < 64; off <<= 1) {
    l += __shfl_xor(l, off, 64);
#pragma unroll
    for (int i = 0; i < 8; ++i) {
      O[i].x += __shfl_xor(O[i].x, off, 64);
      O[i].y += __shfl_xor(O[i].y, off, 64);
      O[i].z += __shfl_xor(O[i].z, off, 64);
      O[i].w += __shfl_xor(O[i].w, off, 64);
    }
  }
  if (lane < 32) {
    float inv = 1.f / l;
    int i4 = lane >> 2, sub = lane & 3;
    float ov = 0.f;
#pragma unroll
    for (int i = 0; i < 8; ++i) {
      if (i4 == i) {
        float4 vv = O[i];
        ov = (sub == 0) ? vv.x : (sub == 1) ? vv.y : (sub == 2) ? vv.z : vv.w;
      }
    }
    out[(size_t)(b * 100 + q) * 256 + h * 32 + lane] = ov * inv;
  }
}

// ---------- fp32 -> bf16 convert ----------
__global__ void cvt_bf16(const float* __restrict__ in, unsigned short* __restrict__ out, int n) {
  int i = (blockIdx.x * 256 + threadIdx.x) * 4;
  if (i + 3 < n) {
    float4 v = *(const float4*)(in + i);
    out[i] = f2b(v.x); out[i + 1] = f2b(v.y); out[i + 2] = f2b(v.z); out[i + 3] = f2b(v.w);
  }
}

// ---------- KV projection: [131072,256]f32 @ Wkv[512,256]^T(bf16) -> Kbuf/Vbuf bf16 ----------
// grid 4096: mb=bid>>1 (64-row tile), nb=bid&1 (0->K cols 0..255, 1->V)
__global__ __launch_bounds__(256) void kv_proj(const float* __restrict__ pix,
                                               const unsigned short* __restrict__ wkv,
                                               const float* __restrict__ bkv,
                                               unsigned short* __restrict__ Kbuf,
                                               unsigned short* __restrict__ Vbuf) {
  __shared__ unsigned short lds[16896];  // A: [0,2560) 64x40, B: [2560,12800) 256x40, C reuse: 64x264
  const int t = threadIdx.x;
  const int mb = blockIdx.x >> 1, nb = blockIdx.x & 1;
  const int w = t >> 6, lane = t & 63, quad = lane >> 4, l16 = lane & 15;

  facc4 acc[4][4] = {};
  for (int k0 = 0; k0 < 256; k0 += 32) {
    {  // stage A (64 rows x 32 k, fp32 -> bf16)
      int r = t >> 2, sg = (t & 3) * 8;
      const float* src = pix + (size_t)(mb * 64 + r) * 256 + k0 + sg;
      float4 f0 = *(const float4*)src;
      float4 f1 = *(const float4*)(src + 4);
      union { unsigned short u[8]; uint4 v; } pk;
      pk.u[0] = f2b(f0.x); pk.u[1] = f2b(f0.y); pk.u[2] = f2b(f0.z); pk.u[3] = f2b(f0.w);
      pk.u[4] = f2b(f1.x); pk.u[5] = f2b(f1.y); pk.u[6] = f2b(f1.z); pk.u[7] = f2b(f1.w);
      *(uint4*)(lds + r * 40 + sg) = pk.v;
    }
    {  // stage B (256 rows x 32 k, bf16)
      const unsigned short* src = wkv + (size_t)(nb * 256 + t) * 256 + k0;
      uint4 b0 = *(const uint4*)src;
      uint4 b1 = *(const uint4*)(src + 8);
      uint4 b2 = *(const uint4*)(src + 16);
      uint4 b3 = *(const uint4*)(src + 24);
      unsigned short* d = lds + 2560 + t * 40;
      *(uint4*)(d) = b0; *(uint4*)(d + 8) = b1; *(uint4*)(d + 16) = b2; *(uint4*)(d + 24) = b3;
    }
    __syncthreads();
    frag8 af[4], bf[4];
#pragma unroll
    for (int mt = 0; mt < 4; ++mt) af[mt] = *(const frag8*)(lds + (mt * 16 + l16) * 40 + quad * 8);
#pragma unroll
    for (int nt = 0; nt < 4; ++nt)
      bf[nt] = *(const frag8*)(lds + 2560 + (w * 64 + nt * 16 + l16) * 40 + quad * 8);
#pragma unroll
    for (int mt = 0; mt < 4; ++mt)
#pragma unroll
      for (int nt = 0; nt < 4; ++nt) acc[mt][nt] = MFMA16(af[mt], bf[nt], acc[mt][nt]);
    __syncthreads();
  }
  // epilogue: bias add, bf16, to LDS (64 x 264), then coalesced scatter to K/V
#pragma unroll
  for (int mt = 0; mt < 4; ++mt)
#pragma unroll
    for (int nt = 0; nt < 4; ++nt) {
      int col = w * 64 + nt * 16 + l16;
      float bvv = bkv[nb * 256 + col];
#pragma unroll
      for (int rg = 0; rg < 4; ++rg) {
        int row = mt * 16 + quad * 4 + rg;
        lds[row * 264 + col] = f2b(acc[mt][nt][rg] + bvv);
      }
    }
  __syncthreads();
#pragma unroll
  for (int i = 0; i < 2; ++i) {
    int p = i * 256 + t;
    int r = p & 63, hd = p >> 6;  // hd 0..7
    int mg = mb * 64 + r;
    int b = mg >> 14, hw = mg & 16383;
    unsigned short* dst = (nb ? Vbuf : Kbuf) + ((size_t)(b * 8 + hd) * 16384 + hw) * 32;
    const unsigned short* srcl = lds + r * 264 + hd * 32;
    uint4 c0 = *(const uint4*)(srcl);
    uint4 c1 = *(const uint4*)(srcl + 8);
    uint4 c2 = *(const uint4*)(srcl + 16);
    uint4 c3 = *(const uint4*)(srcl + 24);
    *(uint4*)dst = c0; *(uint4*)(dst + 8) = c1; *(uint4*)(dst + 16) = c2; *(uint4*)(dst + 24) = c3;
  }
}

// ---------- masked cross-attention, MFMA flash-style ----------
// grid 512 = 64 bh x 8 chunks; block 4 waves, wave handles 512 keys (16 iters x 32)
__global__ __launch_bounds__(256) void cross_attn(const float* __restrict__ qc,
                                                  const unsigned short* __restrict__ Kbuf,
                                                  const unsigned short* __restrict__ Vbuf,
                                                  const unsigned char* __restrict__ mask,
                                                  float* __restrict__ Opart,
                                                  float* __restrict__ lpart) {
  const int bh = blockIdx.x >> 3;
  const int chunk = blockIdx.x & 7;
  const int b = bh >> 3, h = bh & 7;
  const int t = threadIdx.x;
  const int w = t >> 6, lane = t & 63, quad = lane >> 4, l16 = lane & 15;

  __shared__ unsigned short Qs[112 * 40];
  __shared__ unsigned short Ps[4][112 * 40];

  for (int i = t; i < 112 * 32; i += 256) {
    int r = i >> 5, d = i & 31;
    float v = (r < 100) ? qc[(size_t)(b * 100 + r) * 256 + h * 32 + d] * SCALE : 0.f;
    Qs[r * 40 + d] = f2b(v);
  }
  __syncthreads();

  frag8 qf[7];
#pragma unroll
  for (int mt = 0; mt < 7; ++mt) qf[mt] = *(const frag8*)(Qs + (mt * 16 + l16) * 40 + quad * 8);

  facc4 o[7][2] = {};
  float lacc[7] = {};
  const facc4 zacc = {0.f, 0.f, 0.f, 0.f};

  const int keybase = chunk * 2048 + w * 512;
  const unsigned short* Kb = Kbuf + (size_t)bh * 16384 * 32;
  const unsigned short* Vb = Vbuf + (size_t)bh * 16384 * 32;
  unsigned short* Pw = Ps[w];

  for (int it = 0; it < 16; ++it) {
    const int kk = keybase + it * 32;
    // S = Q . K^T  (K rows load directly as B fragments)
    facc4 s[7][2];
#pragma unroll
    for (int nt = 0; nt < 2; ++nt) {
      frag8 kf = *(const frag8*)(Kb + (size_t)(kk + nt * 16 + l16) * 32 + quad * 8);
#pragma unroll
      for (int mt = 0; mt < 7; ++mt) s[mt][nt] = MFMA16(qf[mt], kf, zacc);
    }
    // mask + exp -> P (bf16) into per-wave LDS, in A-operand layout via transpose write
#pragma unroll
    for (int mt = 0; mt < 7; ++mt)
#pragma unroll
      for (int nt = 0; nt < 2; ++nt)
#pragma unroll
        for (int rg = 0; rg < 4; ++rg) {
          int row = mt * 16 + quad * 4 + rg;
          float p = 0.f;
          if (mt < 6 || row < 100) {
            int key = kk + nt * 16 + l16;
            unsigned char mv = mask[(size_t)(bh * 100 + row) * 16384 + key];
            p = mv ? __expf(s[mt][nt][rg]) : 0.f;
          }
          Pw[row * 40 + nt * 16 + l16] = f2b(p);
        }
    // V B-fragments (gather: k = key within chunk, n = head dim)
    frag8 vf0, vf1;
#pragma unroll
    for (int j = 0; j < 8; ++j) {
      vf0[j] = (short)Vb[(size_t)(kk + quad * 8 + j) * 32 + l16];
      vf1[j] = (short)Vb[(size_t)(kk + quad * 8 + j) * 32 + 16 + l16];
    }
#pragma unroll
    for (int mt = 0; mt < 7; ++mt) {
      frag8 pf = *(const frag8*)(Pw + (mt * 16 + l16) * 40 + quad * 8);
#pragma unroll
      for (int j = 0; j < 8; ++j) lacc[mt] += b2f((unsigned short)pf[j]);
      o[mt][0] = MFMA16(pf, vf0, o[mt][0]);
      o[mt][1] = MFMA16(pf, vf1, o[mt][1]);
    }
  }
  // reduce l across quads (lanes sharing l16)
#pragma unroll
  for (int mt = 0; mt < 7; ++mt) {
    lacc[mt] += __shfl_xor(lacc[mt], 16, 64);
    lacc[mt] += __shfl_xor(lacc[mt], 32, 64);
  }
  const int pidx = chunk * 4 + w;
  float* Op = Opart + ((size_t)bh * 32 + pidx) * 112 * 32;
  float* lp = lpart + ((size_t)bh * 32 + pidx) * 112;
#pragma unroll
  for (int mt = 0; mt < 7; ++mt) {
#pragma unroll
    for (int rg = 0; rg < 4; ++rg) {
      int row = mt * 16 + quad * 4 + rg;
      Op[row * 32 + l16] = o[mt][0][rg];
      Op[row * 32 + 16 + l16] = o[mt][1][rg];
    }
    if (lane < 16) lp[mt * 16 + lane] = lacc[mt];
  }
}

// ---------- combine partials: out = sum(O) / sum(l) ----------
__global__ __launch_bounds__(256) void cross_combine(const float* __restrict__ Opart,
                                                     const float* __restrict__ lpart,
                                                     float* __restrict__ out) {
  const int bid = blockIdx.x;
  const int bh = bid / 13, qg = bid - bh * 13;
  const int t = threadIdx.x;
  const int q = qg * 8 + (t >> 5), d = t & 31;
  if (q >= 100) return;
  const int b = bh >> 3, h = bh & 7;
  float osum = 0.f, lsum = 0.f;
#pragma unroll 4
  for (int p = 0; p < 32; ++p) {
    osum += Opart[(((size_t)bh * 32 + p) * 112 + q) * 32 + d];
    lsum += lpart[((size_t)bh * 32 + p) * 112 + q];
  }
  out[(size_t)(b * 100 + q) * 256 + h * 32 + d] = osum / lsum;
}

// ---------- host ----------
extern "C" void kernel_launch(void* const* d_in, const int* in_sizes, int n_in,
                              void* d_out, int out_size, void* d_ws, size_t ws_size,
                              hipStream_t stream) {
  const float* queries = (const float*)d_in[0];
  const float* pix = (const float*)d_in[1];
  const unsigned char* mask = (const unsigned char*)d_in[2];
  const float* sa_in_w = (const float*)d_in[3];
  const float* sa_in_b = (const float*)d_in[4];
  const float* sa_out_w = (const float*)d_in[5];
  const float* sa_out_b = (const float*)d_in[6];
  const float* n1g = (const float*)d_in[7];
  const float* n1b = (const float*)d_in[8];
  const float* ca_in_w = (const float*)d_in[9];
  const float* ca_in_b = (const float*)d_in[10];
  const float* ca_out_w = (const float*)d_in[11];
  const float* ca_out_b = (const float*)d_in[12];
  const float* n2g = (const float*)d_in[13];
  const float* n2b = (const float*)d_in[14];
  const float* ff_w1 = (const float*)d_in[15];
  const float* ff_b1 = (const float*)d_in[16];
  const float* ff_w2 = (const float*)d_in[17];
  const float* ff_b2 = (const float*)d_in[18];
  const float* n3g = (const float*)d_in[19];
  const float* n3b = (const float*)d_in[20];
  float* out = (float*)d_out;
  char* ws = (char*)d_ws;

  unsigned short* Kbuf = (unsigned short*)(ws + 0);            // 67108864 B
  unsigned short* Vbuf = (unsigned short*)(ws + 67108864);     // 67108864 B
  unsigned short* wkv  = (unsigned short*)(ws + 134217728);    // 262144 B
  float* qkvs    = (float*)(ws + 134479872);                   // 2457600 B
  float* sa_out  = (float*)(ws + 136937472);                   // 819200 B
  float* ptmp    = (float*)(ws + 137756672);                   // 819200 B
  float* x1      = (float*)(ws + 138575872);                   // 819200 B
  float* qc      = (float*)(ws + 139395072);                   // 819200 B
  float* Opart   = (float*)(ws + 140214272);                   // 29360128 B
  float* lpart   = (float*)(ws + 169574400);                   // 917504 B
  float* ca_out  = (float*)(ws + 170491904);                   // 819200 B
  float* x2      = (float*)(ws + 171311104);                   // 819200 B
  float* hffn    = (float*)(ws + 172130304);                   // 6553600 B

  // 1) self-attention block
  small_gemm<0><<<dim3(13, 12), 256, 0, stream>>>(queries, sa_in_w, sa_in_b, qkvs, 800, 768, 256);
  self_attn<<<1600, 256, 0, stream>>>(qkvs, sa_out);
  small_gemm<0><<<dim3(13, 4), 256, 0, stream>>>(sa_out, sa_out_w, sa_out_b, ptmp, 800, 256, 256);
  res_ln<<<800, 256, 0, stream>>>(ptmp, queries, n1g, n1b, x1);

  // 2) masked cross-attention block
  small_gemm<0><<<dim3(13, 4), 256, 0, stream>>>(x1, ca_in_w, ca_in_b, qc, 800, 256, 256);
  cvt_bf16<<<128, 256, 0, stream>>>(ca_in_w + 65536, wkv, 131072);
  kv_proj<<<4096, 256, 0, stream>>>(pix, wkv, ca_in_b + 256, Kbuf, Vbuf);
  cross_attn<<<512, 256, 0, stream>>>(qc, Kbuf, Vbuf, mask, Opart, lpart);
  cross_combine<<<64 * 13, 256, 0, stream>>>(Opart, lpart, ca_out);
  small_gemm<0><<<dim3(13, 4), 256, 0, stream>>>(ca_out, ca_out_w, ca_out_b, ptmp, 800, 256, 256);
  res_ln<<<800, 256, 0, stream>>>(ptmp, x1, n2g, n2b, x2);

  // 3) FFN block
  small_gemm<1><<<dim3(13, 32), 256, 0, stream>>>(x2, ff_w1, ff_b1, hffn, 800, 2048, 256);
  small_gemm<0><<<dim3(13, 4), 256, 0, stream>>>(hffn, ff_w2, ff_b2, ptmp, 800, 256, 2048);
  res_ln<<<800, 256, 0, stream>>>(ptmp, x2, n3g, n3b, out);
}

// Round 2
// 867.141 us; speedup vs baseline: 1.3036x; 1.3036x over previous
//
#include <hip/hip_runtime.h>

// B=8, Q=100, HW=16384, D=256, H=8, hd=32, FF=2048
#define SCALE 0.17677669529663687f  // 1/sqrt(32)

typedef __attribute__((ext_vector_type(8))) short frag8;   // 8 bf16 (A/B operand)
typedef __attribute__((ext_vector_type(4))) float facc4;   // 4 f32 (C/D)

#define MFMA16(a, b, c) __builtin_amdgcn_mfma_f32_16x16x32_bf16((a), (b), (c), 0, 0, 0)

__device__ __forceinline__ unsigned short f2b(float f) {
  union { float f; unsigned u; } v; v.f = f;
  return (unsigned short)((v.u + 0x7fffu + ((v.u >> 16) & 1u)) >> 16);
}
__device__ __forceinline__ unsigned int pack2(float a, float b) {
  return (unsigned int)f2b(a) | ((unsigned int)f2b(b) << 16);
}
__device__ __forceinline__ void gl_lds16(const void* g, void* l) {
  __builtin_amdgcn_global_load_lds((const __attribute__((address_space(1))) unsigned int*)g,
                                   (__attribute__((address_space(3))) unsigned int*)l, 16, 0, 0);
}

// ---------- weights fp32 -> bf16, one shot ----------
__global__ __launch_bounds__(256) void cvt_weights(const float* __restrict__ s0, const float* __restrict__ s1,
                                                   const float* __restrict__ s2, const float* __restrict__ s3,
                                                   const float* __restrict__ s4, const float* __restrict__ s5,
                                                   unsigned short* __restrict__ dst) {
  int bid = blockIdx.x;
  const float* src; int off;
  if (bid < 96)       { src = s0; off = 0; }
  else if (bid < 128) { src = s1; off = 196608; bid -= 96; }
  else if (bid < 224) { src = s2; off = 262144; bid -= 128; }
  else if (bid < 256) { src = s3; off = 458752; bid -= 224; }
  else if (bid < 512) { src = s4; off = 524288; bid -= 256; }
  else                { src = s5; off = 1048576; bid -= 512; }
  int i = bid * 2048 + threadIdx.x * 8;
  float4 a = *(const float4*)(src + i);
  float4 b = *(const float4*)(src + i + 4);
  uint4 p;
  p.x = pack2(a.x, a.y); p.y = pack2(a.z, a.w);
  p.z = pack2(b.x, b.y); p.w = pack2(b.z, b.w);
  *(uint4*)(dst + off + i) = p;
}

// ---------- mask bytes -> bit-packed words: mp[(bh*112+q)*512 + key/32], padded q rows = 0 ----------
__global__ __launch_bounds__(256) void pack_mask(const unsigned char* __restrict__ mask,
                                                 unsigned int* __restrict__ mp) {
  int idx = blockIdx.x * 256 + threadIdx.x;  // 64*112*512 = 3670016 words
  if (idx >= 64 * 112 * 512) return;
  int wi = idx & 511;
  int row = (idx >> 9) % 112;
  int bh = idx / (512 * 112);
  unsigned int wv = 0;
  if (row < 100) {
    const unsigned int* src = (const unsigned int*)(mask + (size_t)(bh * 100 + row) * 16384 + wi * 32);
#pragma unroll
    for (int u = 0; u < 8; ++u) {
      unsigned int nib = (((src[u] & 0x01010101u) * 0x01020408u) >> 24) & 0xFu;
      wv |= nib << (u * 4);
    }
  }
  mp[idx] = wv;
}

// ---------- MFMA GEMM: C[M,N](fp32) = A[M,K]fp32 @ Wb[N,K]bf16^T (+bias, relu); splitK via blockIdx.z ----------
template <int RELU, int BIAS>
__global__ __launch_bounds__(256) void mfma_gemm(const float* __restrict__ A,
                                                 const unsigned short* __restrict__ Wb,
                                                 const float* __restrict__ bias,
                                                 float* __restrict__ C,
                                                 int M, int N, int Ktot, int Kchunk) {
  __shared__ unsigned short As[64 * 40];  // padded stride 40 (80 B)
  __shared__ unsigned short Bs[64 * 32];  // unpadded for global_load_lds
  const int t = threadIdx.x;
  const int mb = blockIdx.x, nb = blockIdx.y, zb = blockIdx.z;
  const int w = t >> 6, lane = t & 63, quad = lane >> 4, l16 = lane & 15;
  const int kbeg = zb * Kchunk;
  float* Cz = C + (size_t)zb * M * N;
  facc4 acc[4] = {};
  for (int k0 = kbeg; k0 < kbeg + Kchunk; k0 += 32) {
    {  // A: 64x32 fp32 -> bf16 LDS
      int r = t >> 2, c = (t & 3) * 8;
      int gr = mb * 64 + r;
      float4 f0 = {}, f1 = {};
      if (gr < M) {
        const float* src = A + (size_t)gr * Ktot + k0 + c;
        f0 = *(const float4*)src; f1 = *(const float4*)(src + 4);
      }
      uint4 p;
      p.x = pack2(f0.x, f0.y); p.y = pack2(f0.z, f0.w);
      p.z = pack2(f1.x, f1.y); p.w = pack2(f1.z, f1.w);
      *(uint4*)&As[r * 40 + c] = p;
    }
    {  // B: 64x32 bf16 via async global->LDS (wave w stages rows w*16..+15)
      int row = w * 16 + (lane >> 2);
      gl_lds16(Wb + (size_t)(nb * 64 + row) * Ktot + k0 + (lane & 3) * 8, Bs + w * 512);
    }
    __syncthreads();
    frag8 af = *(const frag8*)(As + (w * 16 + l16) * 40 + quad * 8);
#pragma unroll
    for (int nt = 0; nt < 4; ++nt) {
      frag8 bf = *(const frag8*)(Bs + (nt * 16 + l16) * 32 + quad * 8);
      acc[nt] = MFMA16(af, bf, acc[nt]);
    }
    __syncthreads();
  }
#pragma unroll
  for (int nt = 0; nt < 4; ++nt)
#pragma unroll
    for (int rg = 0; rg < 4; ++rg) {
      int row = mb * 64 + w * 16 + quad * 4 + rg;
      int col = nb * 64 + nt * 16 + l16;
      if (row < M) {
        float v = acc[nt][rg] + (BIAS ? bias[col] : 0.f);
        if (RELU) v = fmaxf(v, 0.f);
        Cz[(size_t)row * N + col] = v;
      }
    }
}

// ---------- residual + LayerNorm ----------
__global__ __launch_bounds__(256) void res_ln(const float* __restrict__ y,
                                              const float* __restrict__ resid,
                                              const float* __restrict__ g,
                                              const float* __restrict__ bv,
                                              float* __restrict__ out) {
  const int r = blockIdx.x, t = threadIdx.x;
  float v = y[(size_t)r * 256 + t] + resid[(size_t)r * 256 + t];
  __shared__ float red[8];
  float s1 = v, s2 = v * v;
#pragma unroll
  for (int off = 1; off < 64; off <<= 1) { s1 += __shfl_xor(s1, off, 64); s2 += __shfl_xor(s2, off, 64); }
  if ((t & 63) == 0) { red[t >> 6] = s1; red[4 + (t >> 6)] = s2; }
  __syncthreads();
  float S1 = red[0] + red[1] + red[2] + red[3];
  float S2 = red[4] + red[5] + red[6] + red[7];
  float mu = S1 * (1.f / 256.f);
  float var = S2 * (1.f / 256.f) - mu * mu;
  float inv = rsqrtf(var + 1e-5f);
  out[(size_t)r * 256 + t] = (v - mu) * inv * g[t] + bv[t];
}

// ---------- 4-partial sum + bias + residual + LayerNorm (ffn2 splitK combine) ----------
__global__ __launch_bounds__(256) void res_ln4(const float* __restrict__ p,
                                               const float* __restrict__ bias,
                                               const float* __restrict__ resid,
                                               const float* __restrict__ g,
                                               const float* __restrict__ bv,
                                               float* __restrict__ out) {
  const int r = blockIdx.x, t = threadIdx.x;
  size_t i = (size_t)r * 256 + t;
  float v = p[i] + p[i + 204800] + p[i + 409600] + p[i + 614400] + bias[t] + resid[i];
  __shared__ float red[8];
  float s1 = v, s2 = v * v;
#pragma unroll
  for (int off = 1; off < 64; off <<= 1) { s1 += __shfl_xor(s1, off, 64); s2 += __shfl_xor(s2, off, 64); }
  if ((t & 63) == 0) { red[t >> 6] = s1; red[4 + (t >> 6)] = s2; }
  __syncthreads();
  float S1 = red[0] + red[1] + red[2] + red[3];
  float S2 = red[4] + red[5] + red[6] + red[7];
  float mu = S1 * (1.f / 256.f);
  float var = S2 * (1.f / 256.f) - mu * mu;
  float inv = rsqrtf(var + 1e-5f);
  out[i] = (v - mu) * inv * g[t] + bv[t];
}

// ---------- self-attention (S=100, no mask), one wave per (b,h,q) row ----------
__global__ __launch_bounds__(256) void self_attn(const float* __restrict__ qkv,
                                                 float* __restrict__ out) {
  const int wid = blockIdx.x * 4 + (threadIdx.x >> 6);
  const int lane = threadIdx.x & 63;
  const int bh = wid / 100, q = wid - bh * 100;
  const int b = bh >> 3, h = bh & 7;
  float4 qv[8];
  {
    const float4* qr = (const float4*)(qkv + (size_t)(b * 100 + q) * 768 + h * 32);
#pragma unroll
    for (int i = 0; i < 8; ++i) {
      float4 x = qr[i];
      qv[i] = make_float4(x.x * SCALE, x.y * SCALE, x.z * SCALE, x.w * SCALE);
    }
  }
  float l = 0.f;
  float4 O[8] = {};
  for (int k0 = 0; k0 < 128; k0 += 64) {
    int k = k0 + lane;
    int kc = (k < 100) ? k : 0;
    const float4* kr = (const float4*)(qkv + (size_t)(b * 100 + kc) * 768 + 256 + h * 32);
    float s = 0.f;
#pragma unroll
    for (int i = 0; i < 8; ++i) {
      float4 kx = kr[i];
      s += qv[i].x * kx.x + qv[i].y * kx.y + qv[i].z * kx.z + qv[i].w * kx.w;
    }
    float p = (k < 100) ? __expf(s) : 0.f;
    l += p;
    const float4* vr = (const float4*)(qkv + (size_t)(b * 100 + kc) * 768 + 512 + h * 32);
#pragma unroll
    for (int i = 0; i < 8; ++i) {
      float4 vx = vr[i];
      O[i].x += p * vx.x; O[i].y += p * vx.y; O[i].z += p * vx.z; O[i].w += p * vx.w;
    }
  }
#pragma unroll
  for (int off = 1; off < 64; off <<= 1) {
    l += __shfl_xor(l, off, 64);
#pragma unroll
    for (int i = 0; i < 8; ++i) {
      O[i].x += __shfl_xor(O[i].x, off, 64);
      O[i].y += __shfl_xor(O[i].y, off, 64);
      O[i].z += __shfl_xor(O[i].z, off, 64);
      O[i].w += __shfl_xor(O[i].w, off, 64);
    }
  }
  if (lane < 32) {
    float inv = 1.f / l;
    int i4 = lane >> 2, sub = lane & 3;
    float ov = 0.f;
#pragma unroll
    for (int i = 0; i < 8; ++i) {
      if (i4 == i) {
        float4 vv = O[i];
        ov = (sub == 0) ? vv.x : (sub == 1) ? vv.y : (sub == 2) ? vv.z : vv.w;
      }
    }
    out[(size_t)(b * 100 + q) * 256 + h * 32 + lane] = ov * inv;
  }
}

// ---------- KV projection: one block = 64 pixel rows x all 512 N-cols; K row-major, V transposed ----------
__global__ __launch_bounds__(512) void kv_proj(const float* __restrict__ pix,
                                               const unsigned short* __restrict__ wkv,
                                               const float* __restrict__ bkv,
                                               unsigned short* __restrict__ Kbuf,
                                               unsigned short* __restrict__ Vt) {
  __shared__ unsigned short smem[2560 + 16384];  // As 64x40 | Bs 512x32 (37888 B); epilogue reuses
  unsigned short* As = smem;
  unsigned short* Bs = smem + 2560;
  const int t = threadIdx.x;
  const int mb = blockIdx.x;
  const int w = t >> 6, lane = t & 63, quad = lane >> 4, l16 = lane & 15;
  const int b = mb >> 8;
  const int hw0 = (mb & 255) * 64;

  facc4 acc[4][4] = {};
  for (int k0 = 0; k0 < 256; k0 += 32) {
    {  // A: 64x32 fp32 -> bf16; 512 threads x 4 floats
      int r = t >> 3, c = (t & 7) * 4;
      float4 f = *(const float4*)(pix + (size_t)(mb * 64 + r) * 256 + k0 + c);
      uint2 p; p.x = pack2(f.x, f.y); p.y = pack2(f.z, f.w);
      *(uint2*)&As[r * 40 + c] = p;
    }
    {  // B: 512x32 bf16 async; wave w stages 64 rows via 4 insts
#pragma unroll
      for (int i = 0; i < 4; ++i) {
        int seg = w * 4 + i;
        int row = seg * 16 + (lane >> 2);
        gl_lds16(wkv + (size_t)row * 256 + k0 + (lane & 3) * 8, Bs + seg * 512);
      }
    }
    __syncthreads();
    frag8 af[4], bf[4];
#pragma unroll
    for (int mt = 0; mt < 4; ++mt) af[mt] = *(const frag8*)(As + (mt * 16 + l16) * 40 + quad * 8);
#pragma unroll
    for (int nt = 0; nt < 4; ++nt) bf[nt] = *(const frag8*)(Bs + (w * 64 + nt * 16 + l16) * 32 + quad * 8);
#pragma unroll
    for (int mt = 0; mt < 4; ++mt)
#pragma unroll
      for (int nt = 0; nt < 4; ++nt) acc[mt][nt] = MFMA16(af[mt], bf[nt], acc[mt][nt]);
    __syncthreads();
  }
  // ---- phase 0: K (cols 0..255, waves 0..3), row-major [bh][key][dim]
  {
    unsigned short* Cs = smem;  // 64 x 264
    if (w < 4) {
#pragma unroll
      for (int mt = 0; mt < 4; ++mt)
#pragma unroll
        for (int nt = 0; nt < 4; ++nt) {
          int col = w * 64 + nt * 16 + l16;
          float bvv = bkv[col];
#pragma unroll
          for (int rg = 0; rg < 4; ++rg)
            Cs[(mt * 16 + quad * 4 + rg) * 264 + col] = f2b(acc[mt][nt][rg] + bvv);
        }
    }
    __syncthreads();
    int key = t >> 3, h = t & 7;
    const unsigned short* src = &Cs[key * 264 + h * 32];
    unsigned short* dst = Kbuf + ((size_t)((b * 8 + h) * 16384 + hw0 + key)) * 32;
    uint4 c0 = *(const uint4*)src, c1 = *(const uint4*)(src + 8);
    uint4 c2 = *(const uint4*)(src + 16), c3 = *(const uint4*)(src + 24);
    *(uint4*)dst = c0; *(uint4*)(dst + 8) = c1; *(uint4*)(dst + 16) = c2; *(uint4*)(dst + 24) = c3;
  }
  __syncthreads();
  // ---- phase 1: V (cols 256..511, waves 4..7), transposed [bh][dim][key]
  {
    unsigned short* Cst = smem;  // 256 x 72 (pad for banks + 16B align)
    if (w >= 4) {
#pragma unroll
      for (int mt = 0; mt < 4; ++mt)
#pragma unroll
        for (int nt = 0; nt < 4; ++nt) {
          int colv = (w - 4) * 64 + nt * 16 + l16;
          float bvv = bkv[256 + colv];
#pragma unroll
          for (int rg = 0; rg < 4; ++rg)
            Cst[colv * 72 + (mt * 16 + quad * 4 + rg)] = f2b(acc[mt][nt][rg] + bvv);
        }
    }
    __syncthreads();
    int dr = t >> 1, half = t & 1;  // dr = h*32+d
    const unsigned short* src = &Cst[dr * 72 + half * 32];
    unsigned short* dst = Vt + ((size_t)(b * 8 + (dr >> 5)) * 32 + (dr & 31)) * 16384 + hw0 + half * 32;
    uint4 c0 = *(const uint4*)src, c1 = *(const uint4*)(src + 8);
    uint4 c2 = *(const uint4*)(src + 16), c3 = *(const uint4*)(src + 24);
    *(uint4*)dst = c0; *(uint4*)(dst + 8) = c1; *(uint4*)(dst + 16) = c2; *(uint4*)(dst + 24) = c3;
  }
}

// ---------- masked cross-attention: S^T = K*Q^T, P stays in registers (permuted k-slots), V pre-transposed ----------
__global__ __launch_bounds__(256) void cross_attn(const float* __restrict__ qc,
                                                  const unsigned short* __restrict__ Kbuf,
                                                  const unsigned short* __restrict__ Vt,
                                                  const unsigned int* __restrict__ maskp,
                                                  float* __restrict__ Opart,
                                                  float* __restrict__ lpart) {
  const int bh = blockIdx.x >> 3;
  const int chunk = blockIdx.x & 7;
  const int b = bh >> 3, h = bh & 7;
  const int t = threadIdx.x;
  const int w = t >> 6, lane = t & 63, quad = lane >> 4, l16 = lane & 15;

  __shared__ unsigned short Qs[112 * 40];
  for (int i = t; i < 112 * 32; i += 256) {
    int r = i >> 5, d = i & 31;
    float v = (r < 100) ? qc[(size_t)(b * 100 + r) * 256 + h * 32 + d] * SCALE : 0.f;
    Qs[r * 40 + d] = f2b(v);
  }
  __syncthreads();

  frag8 qf[7];
#pragma unroll
  for (int qt = 0; qt < 7; ++qt) qf[qt] = *(const frag8*)(Qs + (qt * 16 + l16) * 40 + quad * 8);

  facc4 o[7][2] = {};
  float lacc[7] = {};
  const facc4 zacc = {0.f, 0.f, 0.f, 0.f};
  const int keybase = chunk * 2048 + w * 512;
  const unsigned short* Kb = Kbuf + (size_t)bh * 16384 * 32;
  const unsigned short* Vb = Vt + (size_t)bh * 32 * 16384;
  const unsigned int* mrow = maskp + (size_t)bh * 112 * 512;

  for (int it = 0; it < 16; ++it) {
    const int kk = keybase + it * 32;
    // K rows as A-operand fragments (keys kk+l16 and kk+16+l16)
    frag8 kf0 = *(const frag8*)(Kb + (size_t)(kk + l16) * 32 + quad * 8);
    frag8 kf1 = *(const frag8*)(Kb + (size_t)(kk + 16 + l16) * 32 + quad * 8);
    // V B-frags with permuted k-slots: slot(quad,j) -> key kk + (j>>2)*16 + quad*4 + (j&3)
    frag8 vf[2];
#pragma unroll
    for (int dt = 0; dt < 2; ++dt) {
      const unsigned short* vp = Vb + (size_t)(dt * 16 + l16) * 16384 + kk + quad * 4;
      ushort4 lo = *(const ushort4*)vp;
      ushort4 hi = *(const ushort4*)(vp + 16);
      frag8 v;
      v[0] = (short)lo.x; v[1] = (short)lo.y; v[2] = (short)lo.z; v[3] = (short)lo.w;
      v[4] = (short)hi.x; v[5] = (short)hi.y; v[6] = (short)hi.z; v[7] = (short)hi.w;
      vf[dt] = v;
    }
    const int wi = kk >> 5;
#pragma unroll
    for (int qt = 0; qt < 7; ++qt) {
      facc4 s0 = MFMA16(kf0, qf[qt], zacc);   // S^T: row=key16=quad*4+rg, col=q=l16
      facc4 s1 = MFMA16(kf1, qf[qt], zacc);
      unsigned int mw = mrow[(qt * 16 + l16) * 512 + wi];
      float p[8];
#pragma unroll
      for (int rg = 0; rg < 4; ++rg) {
        float e0 = __expf(s0[rg]);
        float e1 = __expf(s1[rg]);
        p[rg]     = ((mw >> (quad * 4 + rg)) & 1u) ? e0 : 0.f;
        p[4 + rg] = ((mw >> (16 + quad * 4 + rg)) & 1u) ? e1 : 0.f;
      }
      lacc[qt] += p[0] + p[1] + p[2] + p[3] + p[4] + p[5] + p[6] + p[7];
      frag8 pa;
#pragma unroll
      for (int j = 0; j < 8; ++j) pa[j] = (short)f2b(p[j]);
      o[qt][0] = MFMA16(pa, vf[0], o[qt][0]);
      o[qt][1] = MFMA16(pa, vf[1], o[qt][1]);
    }
  }
#pragma unroll
  for (int qt = 0; qt < 7; ++qt) {
    lacc[qt] += __shfl_xor(lacc[qt], 16, 64);
    lacc[qt] += __shfl_xor(lacc[qt], 32, 64);
  }
  const int pidx = chunk * 4 + w;
  float* Op = Opart + ((size_t)bh * 32 + pidx) * 112 * 32;
  float* lp = lpart + ((size_t)bh * 32 + pidx) * 112;
#pragma unroll
  for (int qt = 0; qt < 7; ++qt) {
#pragma unroll
    for (int rg = 0; rg < 4; ++rg) {
      int row = qt * 16 + quad * 4 + rg;
      Op[row * 32 + l16] = o[qt][0][rg];
      Op[row * 32 + 16 + l16] = o[qt][1][rg];
    }
    if (lane < 16) lp[qt * 16 + lane] = lacc[qt];
  }
}

// ---------- combine partials: out = sum(O) / sum(l) ----------
__global__ __launch_bounds__(256) void cross_combine(const float* __restrict__ Opart,
                                                     const float* __restrict__ lpart,
                                                     float* __restrict__ out) {
  const int bid = blockIdx.x;
  const int bh = bid / 13, qg = bid - bh * 13;
  const int t = threadIdx.x;
  const int q = qg * 8 + (t >> 5), d = t & 31;
  if (q >= 100) return;
  const int b = bh >> 3, h = bh & 7;
  float osum = 0.f, lsum = 0.f;
#pragma unroll 4
  for (int p = 0; p < 32; ++p) {
    osum += Opart[(((size_t)bh * 32 + p) * 112 + q) * 32 + d];
    lsum += lpart[((size_t)bh * 32 + p) * 112 + q];
  }
  out[(size_t)(b * 100 + q) * 256 + h * 32 + d] = osum / lsum;
}

// ---------- host ----------
extern "C" void kernel_launch(void* const* d_in, const int* in_sizes, int n_in,
                              void* d_out, int out_size, void* d_ws, size_t ws_size,
                              hipStream_t stream) {
  const float* queries = (const float*)d_in[0];
  const float* pix = (const float*)d_in[1];
  const unsigned char* mask = (const unsigned char*)d_in[2];
  const float* sa_in_w = (const float*)d_in[3];
  const float* sa_in_b = (const float*)d_in[4];
  const float* sa_out_w = (const float*)d_in[5];
  const float* sa_out_b = (const float*)d_in[6];
  const float* n1g = (const float*)d_in[7];
  const float* n1b = (const float*)d_in[8];
  const float* ca_in_w = (const float*)d_in[9];
  const float* ca_in_b = (const float*)d_in[10];
  const float* ca_out_w = (const float*)d_in[11];
  const float* ca_out_b = (const float*)d_in[12];
  const float* n2g = (const float*)d_in[13];
  const float* n2b = (const float*)d_in[14];
  const float* ff_w1 = (const float*)d_in[15];
  const float* ff_b1 = (const float*)d_in[16];
  const float* ff_w2 = (const float*)d_in[17];
  const float* ff_b2 = (const float*)d_in[18];
  const float* n3g = (const float*)d_in[19];
  const float* n3b = (const float*)d_in[20];
  float* out = (float*)d_out;
  char* ws = (char*)d_ws;

  unsigned short* Kbuf = (unsigned short*)(ws + 0);            // 67108864
  unsigned short* Vt   = (unsigned short*)(ws + 67108864);     // 67108864
  unsigned short* wb   = (unsigned short*)(ws + 134217728);    // 3145728
  unsigned int* maskp  = (unsigned int*)(ws + 137363456);      // 14680064
  float* qkvs   = (float*)(ws + 152043520);                    // 2457600
  float* sao    = (float*)(ws + 154501120);                    // 819200
  float* ptmp   = (float*)(ws + 155320320);                    // 3276800 (4 splitK partials)
  float* x1     = (float*)(ws + 158597120);                    // 819200
  float* qc     = (float*)(ws + 159416320);                    // 819200
  float* Opart  = (float*)(ws + 160235520);                    // 29360128
  float* lpart  = (float*)(ws + 189595648);                    // 917504
  float* ca_out = (float*)(ws + 190513152);                    // 819200
  float* x2     = (float*)(ws + 191332352);                    // 819200
  float* hffn   = (float*)(ws + 192151552);                    // 6553600

  const unsigned short* wb_sain  = wb;
  const unsigned short* wb_saout = wb + 196608;
  const unsigned short* wb_caq   = wb + 262144;
  const unsigned short* wb_cakv  = wb + 327680;
  const unsigned short* wb_caout = wb + 458752;
  const unsigned short* wb_ff1   = wb + 524288;
  const unsigned short* wb_ff2   = wb + 1048576;

  cvt_weights<<<768, 256, 0, stream>>>(sa_in_w, sa_out_w, ca_in_w, ca_out_w, ff_w1, ff_w2, wb);
  pack_mask<<<14336, 256, 0, stream>>>(mask, maskp);

  // 1) self-attention block
  mfma_gemm<0, 1><<<dim3(13, 12, 1), 256, 0, stream>>>(queries, wb_sain, sa_in_b, qkvs, 800, 768, 256, 256);
  self_attn<<<1600, 256, 0, stream>>>(qkvs, sao);
  mfma_gemm<0, 1><<<dim3(13, 4, 1), 256, 0, stream>>>(sao, wb_saout, sa_out_b, ptmp, 800, 256, 256, 256);
  res_ln<<<800, 256, 0, stream>>>(ptmp, queries, n1g, n1b, x1);

  // 2) masked cross-attention block
  mfma_gemm<0, 1><<<dim3(13, 4, 1), 256, 0, stream>>>(x1, wb_caq, ca_in_b, qc, 800, 256, 256, 256);
  kv_proj<<<2048, 512, 0, stream>>>(pix, wb_cakv, ca_in_b + 256, Kbuf, Vt);
  cross_attn<<<512, 256, 0, stream>>>(qc, Kbuf, Vt, maskp, Opart, lpart);
  cross_combine<<<64 * 13, 256, 0, stream>>>(Opart, lpart, ca_out);
  mfma_gemm<0, 1><<<dim3(13, 4, 1), 256, 0, stream>>>(ca_out, wb_caout, ca_out_b, ptmp, 800, 256, 256, 256);
  res_ln<<<800, 256, 0, stream>>>(ptmp, x1, n2g, n2b, x2);

  // 3) FFN block
  mfma_gemm<1, 1><<<dim3(13, 32, 1), 256, 0, stream>>>(x2, wb_ff1, ff_b1, hffn, 800, 2048, 256, 256);
  mfma_gemm<0, 0><<<dim3(13, 4, 4), 256, 0, stream>>>(hffn, wb_ff2, nullptr, ptmp, 800, 256, 2048, 512);
  res_ln4<<<800, 256, 0, stream>>>(ptmp, ff_b2, x2, n3g, n3b, out);
}

// Round 3
// 807.675 us; speedup vs baseline: 1.3996x; 1.0736x over previous
//
#include <hip/hip_runtime.h>

// B=8, Q=100, HW=16384, D=256, H=8, hd=32, FF=2048
#define SCALE 0.17677669529663687f               // 1/sqrt(32)
#define SCALE2 (0.17677669529663687f * 1.4426950408889634f)  // 1/sqrt(32) * log2(e)

typedef __attribute__((ext_vector_type(8))) short frag8;   // 8 bf16 (A/B operand)
typedef __attribute__((ext_vector_type(4))) float facc4;   // 4 f32 (C/D)

#define MFMA16(a, b, c) __builtin_amdgcn_mfma_f32_16x16x32_bf16((a), (b), (c), 0, 0, 0)

__device__ __forceinline__ unsigned short f2b(float f) {
  union { float f; unsigned u; } v; v.f = f;
  return (unsigned short)((v.u + 0x7fffu + ((v.u >> 16) & 1u)) >> 16);
}
__device__ __forceinline__ float b2f(unsigned short h) {
  union { unsigned u; float f; } v; v.u = ((unsigned)h) << 16;
  return v.f;
}
__device__ __forceinline__ unsigned int pack2(float a, float b) {
  return (unsigned int)f2b(a) | ((unsigned int)f2b(b) << 16);
}
// truncating bf16 pack (1-2 ops; ~0.4% rel err, fine for P / pix intermediates)
__device__ __forceinline__ unsigned int tpack(float a, float b) {
  union { float f; unsigned u; } x, y; x.f = a; y.f = b;
  return (x.u >> 16) | (y.u & 0xffff0000u);
}
__device__ __forceinline__ void gl_lds16(const void* g, void* l) {
  __builtin_amdgcn_global_load_lds((const __attribute__((address_space(1))) unsigned int*)g,
                                   (__attribute__((address_space(3))) unsigned int*)l, 16, 0, 0);
}

union F8U { frag8 f; unsigned u[4]; };

// ---------- weights fp32 -> bf16, one shot ----------
__global__ __launch_bounds__(256) void cvt_weights(const float* __restrict__ s0, const float* __restrict__ s1,
                                                   const float* __restrict__ s2, const float* __restrict__ s3,
                                                   const float* __restrict__ s4, const float* __restrict__ s5,
                                                   unsigned short* __restrict__ dst) {
  int bid = blockIdx.x;
  const float* src; int off;
  if (bid < 96)       { src = s0; off = 0; }
  else if (bid < 128) { src = s1; off = 196608; bid -= 96; }
  else if (bid < 224) { src = s2; off = 262144; bid -= 128; }
  else if (bid < 256) { src = s3; off = 458752; bid -= 224; }
  else if (bid < 512) { src = s4; off = 524288; bid -= 256; }
  else                { src = s5; off = 1048576; bid -= 512; }
  int i = bid * 2048 + threadIdx.x * 8;
  float4 a = *(const float4*)(src + i);
  float4 b = *(const float4*)(src + i + 4);
  uint4 p;
  p.x = pack2(a.x, a.y); p.y = pack2(a.z, a.w);
  p.z = pack2(b.x, b.y); p.w = pack2(b.z, b.w);
  *(uint4*)(dst + off + i) = p;
}

// ---------- MFMA GEMM: C[M,N](fp32) = A[M,K]fp32 @ Wb[N,K]bf16^T (+bias, relu); splitK via blockIdx.z ----------
template <int RELU, int BIAS>
__global__ __launch_bounds__(256) void mfma_gemm(const float* __restrict__ A,
                                                 const unsigned short* __restrict__ Wb,
                                                 const float* __restrict__ bias,
                                                 float* __restrict__ C,
                                                 int M, int N, int Ktot, int Kchunk) {
  __shared__ unsigned short As[64 * 40];
  __shared__ unsigned short Bs[64 * 32];
  const int t = threadIdx.x;
  const int mb = blockIdx.x, nb = blockIdx.y, zb = blockIdx.z;
  const int w = t >> 6, lane = t & 63, quad = lane >> 4, l16 = lane & 15;
  const int kbeg = zb * Kchunk;
  float* Cz = C + (size_t)zb * M * N;
  facc4 acc[4] = {};
  for (int k0 = kbeg; k0 < kbeg + Kchunk; k0 += 32) {
    {
      int r = t >> 2, c = (t & 3) * 8;
      int gr = mb * 64 + r;
      float4 f0 = {}, f1 = {};
      if (gr < M) {
        const float* src = A + (size_t)gr * Ktot + k0 + c;
        f0 = *(const float4*)src; f1 = *(const float4*)(src + 4);
      }
      uint4 p;
      p.x = pack2(f0.x, f0.y); p.y = pack2(f0.z, f0.w);
      p.z = pack2(f1.x, f1.y); p.w = pack2(f1.z, f1.w);
      *(uint4*)&As[r * 40 + c] = p;
    }
    {
      int row = w * 16 + (lane >> 2);
      gl_lds16(Wb + (size_t)(nb * 64 + row) * Ktot + k0 + (lane & 3) * 8, Bs + w * 512);
    }
    __syncthreads();
    frag8 af = *(const frag8*)(As + (w * 16 + l16) * 40 + quad * 8);
#pragma unroll
    for (int nt = 0; nt < 4; ++nt) {
      frag8 bf = *(const frag8*)(Bs + (nt * 16 + l16) * 32 + quad * 8);
      acc[nt] = MFMA16(af, bf, acc[nt]);
    }
    __syncthreads();
  }
#pragma unroll
  for (int nt = 0; nt < 4; ++nt)
#pragma unroll
    for (int rg = 0; rg < 4; ++rg) {
      int row = mb * 64 + w * 16 + quad * 4 + rg;
      int col = nb * 64 + nt * 16 + l16;
      if (row < M) {
        float v = acc[nt][rg] + (BIAS ? bias[col] : 0.f);
        if (RELU) v = fmaxf(v, 0.f);
        Cz[(size_t)row * N + col] = v;
      }
    }
}

// ---------- residual + LayerNorm ----------
__global__ __launch_bounds__(256) void res_ln(const float* __restrict__ y,
                                              const float* __restrict__ resid,
                                              const float* __restrict__ g,
                                              const float* __restrict__ bv,
                                              float* __restrict__ out) {
  const int r = blockIdx.x, t = threadIdx.x;
  float v = y[(size_t)r * 256 + t] + resid[(size_t)r * 256 + t];
  __shared__ float red[8];
  float s1 = v, s2 = v * v;
#pragma unroll
  for (int off = 1; off < 64; off <<= 1) { s1 += __shfl_xor(s1, off, 64); s2 += __shfl_xor(s2, off, 64); }
  if ((t & 63) == 0) { red[t >> 6] = s1; red[4 + (t >> 6)] = s2; }
  __syncthreads();
  float S1 = red[0] + red[1] + red[2] + red[3];
  float S2 = red[4] + red[5] + red[6] + red[7];
  float mu = S1 * (1.f / 256.f);
  float var = S2 * (1.f / 256.f) - mu * mu;
  float inv = rsqrtf(var + 1e-5f);
  out[(size_t)r * 256 + t] = (v - mu) * inv * g[t] + bv[t];
}

// ---------- 4-partial sum + bias + residual + LayerNorm (ffn2 splitK combine) ----------
__global__ __launch_bounds__(256) void res_ln4(const float* __restrict__ p,
                                               const float* __restrict__ bias,
                                               const float* __restrict__ resid,
                                               const float* __restrict__ g,
                                               const float* __restrict__ bv,
                                               float* __restrict__ out) {
  const int r = blockIdx.x, t = threadIdx.x;
  size_t i = (size_t)r * 256 + t;
  float v = p[i] + p[i + 204800] + p[i + 409600] + p[i + 614400] + bias[t] + resid[i];
  __shared__ float red[8];
  float s1 = v, s2 = v * v;
#pragma unroll
  for (int off = 1; off < 64; off <<= 1) { s1 += __shfl_xor(s1, off, 64); s2 += __shfl_xor(s2, off, 64); }
  if ((t & 63) == 0) { red[t >> 6] = s1; red[4 + (t >> 6)] = s2; }
  __syncthreads();
  float S1 = red[0] + red[1] + red[2] + red[3];
  float S2 = red[4] + red[5] + red[6] + red[7];
  float mu = S1 * (1.f / 256.f);
  float var = S2 * (1.f / 256.f) - mu * mu;
  float inv = rsqrtf(var + 1e-5f);
  out[i] = (v - mu) * inv * g[t] + bv[t];
}

// ---------- self-attention (S=100, no mask), one wave per (b,h,q) row ----------
__global__ __launch_bounds__(256) void self_attn(const float* __restrict__ qkv,
                                                 float* __restrict__ out) {
  const int wid = blockIdx.x * 4 + (threadIdx.x >> 6);
  const int lane = threadIdx.x & 63;
  const int bh = wid / 100, q = wid - bh * 100;
  const int b = bh >> 3, h = bh & 7;
  float4 qv[8];
  {
    const float4* qr = (const float4*)(qkv + (size_t)(b * 100 + q) * 768 + h * 32);
#pragma unroll
    for (int i = 0; i < 8; ++i) {
      float4 x = qr[i];
      qv[i] = make_float4(x.x * SCALE, x.y * SCALE, x.z * SCALE, x.w * SCALE);
    }
  }
  float l = 0.f;
  float4 O[8] = {};
  for (int k0 = 0; k0 < 128; k0 += 64) {
    int k = k0 + lane;
    int kc = (k < 100) ? k : 0;
    const float4* kr = (const float4*)(qkv + (size_t)(b * 100 + kc) * 768 + 256 + h * 32);
    float s = 0.f;
#pragma unroll
    for (int i = 0; i < 8; ++i) {
      float4 kx = kr[i];
      s += qv[i].x * kx.x + qv[i].y * kx.y + qv[i].z * kx.z + qv[i].w * kx.w;
    }
    float p = (k < 100) ? __expf(s) : 0.f;
    l += p;
    const float4* vr = (const float4*)(qkv + (size_t)(b * 100 + kc) * 768 + 512 + h * 32);
#pragma unroll
    for (int i = 0; i < 8; ++i) {
      float4 vx = vr[i];
      O[i].x += p * vx.x; O[i].y += p * vx.y; O[i].z += p * vx.z; O[i].w += p * vx.w;
    }
  }
#pragma unroll
  for (int off = 1; off < 64; off <<= 1) {
    l += __shfl_xor(l, off, 64);
#pragma unroll
    for (int i = 0; i < 8; ++i) {
      O[i].x += __shfl_xor(O[i].x, off, 64);
      O[i].y += __shfl_xor(O[i].y, off, 64);
      O[i].z += __shfl_xor(O[i].z, off, 64);
      O[i].w += __shfl_xor(O[i].w, off, 64);
    }
  }
  if (lane < 32) {
    float inv = 1.f / l;
    int i4 = lane >> 2, sub = lane & 3;
    float ov = 0.f;
#pragma unroll
    for (int i = 0; i < 8; ++i) {
      if (i4 == i) {
        float4 vv = O[i];
        ov = (sub == 0) ? vv.x : (sub == 1) ? vv.y : (sub == 2) ? vv.z : vv.w;
      }
    }
    out[(size_t)(b * 100 + q) * 256 + h * 32 + lane] = ov * inv;
  }
}

// ---------- fused KV-projection + masked cross-attention ----------
// grid 256 = (b 8) x (chunk 32: 512 keys); block 512 = 8 waves, wave = head.
// K never leaves registers: K-GEMM (A=Wk dims, B=pix keys) C-layout == S^T A-frag
// under k-slot perm sigma; Q loaded with matching sigma. V-GEMM (A=pix, B=Wv)
// C-layout == PV B-frag under perm pi matching P's A-slots (round-2-verified).
__global__ __launch_bounds__(512, 2) void ca_fused(const float* __restrict__ qc,
                                                   const unsigned short* __restrict__ wkv,
                                                   const float* __restrict__ bkv,
                                                   const float* __restrict__ pix,
                                                   const unsigned char* __restrict__ mask,
                                                   unsigned short* __restrict__ Opartb,
                                                   float* __restrict__ lpart) {
  const int bid = blockIdx.x;
  const int b = bid >> 5, chunk = bid & 31;
  const int t = threadIdx.x;
  const int h = t >> 6, lane = t & 63, quad = lane >> 4, l16 = lane & 15;
  const int bh = b * 8 + h;

  __shared__ unsigned short PixS[8 * 32 * 40];  // [chb][key 32][40 pad] bf16

  // Q fragments, sigma-permuted k-slots: qf[qt][j] = Q[q][h*32 + 16*(j>>2) + quad*4 + (j&3)] * SCALE2
  frag8 qf[7];
#pragma unroll
  for (int qt = 0; qt < 7; ++qt) {
    int r = qt * 16 + l16;
    float4 f0 = {}, f1 = {};
    if (r < 100) {
      const float* qrow = qc + (size_t)(b * 100 + r) * 256 + h * 32 + quad * 4;
      f0 = *(const float4*)qrow;
      f1 = *(const float4*)(qrow + 16);
    }
    F8U u;
    u.u[0] = pack2(f0.x * SCALE2, f0.y * SCALE2);
    u.u[1] = pack2(f0.z * SCALE2, f0.w * SCALE2);
    u.u[2] = pack2(f1.x * SCALE2, f1.y * SCALE2);
    u.u[3] = pack2(f1.z * SCALE2, f1.w * SCALE2);
    qf[qt] = u.f;
  }

  // biases: K per (mf,rg); V per nf
  float bK[2][4], bV[2];
#pragma unroll
  for (int mf = 0; mf < 2; ++mf) {
#pragma unroll
    for (int rg = 0; rg < 4; ++rg) bK[mf][rg] = bkv[h * 32 + mf * 16 + quad * 4 + rg];
    bV[mf] = bkv[256 + h * 32 + mf * 16 + l16];
  }

  const unsigned short* wkbase = wkv + (size_t)(h * 32) * 256;
  const unsigned short* wvbase = wkv + (size_t)(256 + h * 32) * 256;

  facc4 o[7][2] = {};
  float lacc[7] = {};
  const facc4 zacc = {0.f, 0.f, 0.f, 0.f};

  for (int it = 0; it < 16; ++it) {
    const int kk = it * 32;
    const int gkey = chunk * 512 + kk;
    __syncthreads();
    {  // stage pix slice 32 keys x 256 ch, fp32 -> bf16 (trunc), chb-blocked
      int row = t >> 4, cg = (t & 15) * 16;
      const float* src = pix + ((size_t)(b * 16384 + gkey + row)) * 256 + cg;
      float4 a0 = *(const float4*)src;
      float4 a1 = *(const float4*)(src + 4);
      float4 a2 = *(const float4*)(src + 8);
      float4 a3 = *(const float4*)(src + 12);
      uint4 u0, u1;
      u0.x = tpack(a0.x, a0.y); u0.y = tpack(a0.z, a0.w);
      u0.z = tpack(a1.x, a1.y); u0.w = tpack(a1.z, a1.w);
      u1.x = tpack(a2.x, a2.y); u1.y = tpack(a2.z, a2.w);
      u1.z = tpack(a3.x, a3.y); u1.w = tpack(a3.z, a3.w);
      unsigned short* d = PixS + (cg >> 5) * 1280 + row * 40 + (cg & 31);
      *(uint4*)d = u0; *(uint4*)(d + 8) = u1;
    }
    __syncthreads();

    // KV-GEMM over 8 ch-blocks
    facc4 ka[2][2] = {}, va[2][2] = {};
#pragma unroll
    for (int cb = 0; cb < 8; ++cb) {
      frag8 pf0 = *(const frag8*)(PixS + cb * 1280 + l16 * 40 + quad * 8);
      frag8 pf1 = *(const frag8*)(PixS + cb * 1280 + (16 + l16) * 40 + quad * 8);
      int co = cb * 32 + quad * 8;
      frag8 wk0 = *(const frag8*)(wkbase + (size_t)l16 * 256 + co);
      frag8 wk1 = *(const frag8*)(wkbase + (size_t)(16 + l16) * 256 + co);
      frag8 wv0 = *(const frag8*)(wvbase + (size_t)l16 * 256 + co);
      frag8 wv1 = *(const frag8*)(wvbase + (size_t)(16 + l16) * 256 + co);
      ka[0][0] = MFMA16(wk0, pf0, ka[0][0]); ka[0][1] = MFMA16(wk0, pf1, ka[0][1]);
      ka[1][0] = MFMA16(wk1, pf0, ka[1][0]); ka[1][1] = MFMA16(wk1, pf1, ka[1][1]);
      va[0][0] = MFMA16(pf0, wv0, va[0][0]); va[0][1] = MFMA16(pf0, wv1, va[0][1]);
      va[1][0] = MFMA16(pf1, wv0, va[1][0]); va[1][1] = MFMA16(pf1, wv1, va[1][1]);
    }
    // kfA[half][j] = bf16(ka[j>>2][half][j&3] + bK);  vfB[nf][j] = bf16(va[j>>2][nf][j&3] + bV[nf])
    frag8 kfA0, kfA1, vfB0, vfB1;
    {
      F8U k0u, k1u, v0u, v1u;
#pragma unroll
      for (int pr = 0; pr < 4; ++pr) {
        int mf = pr >> 1, r0 = (pr & 1) * 2, r1 = r0 + 1;
        k0u.u[pr] = tpack(ka[mf][0][r0] + bK[mf][r0], ka[mf][0][r1] + bK[mf][r1]);
        k1u.u[pr] = tpack(ka[mf][1][r0] + bK[mf][r0], ka[mf][1][r1] + bK[mf][r1]);
        v0u.u[pr] = tpack(va[mf][0][r0] + bV[0], va[mf][0][r1] + bV[0]);
        v1u.u[pr] = tpack(va[mf][1][r0] + bV[1], va[mf][1][r1] + bV[1]);
      }
      kfA0 = k0u.f; kfA1 = k1u.f; vfB0 = v0u.f; vfB1 = v1u.f;
    }

    // attention for this 32-key slice
    const unsigned char* mbase = mask + (size_t)bh * 100 * 16384 + gkey + quad * 4;
#pragma unroll
    for (int qt = 0; qt < 7; ++qt) {
      facc4 s0 = MFMA16(kfA0, qf[qt], zacc);  // S^T: key=quad*4+rg, q=l16
      facc4 s1 = MFMA16(kfA1, qf[qt], zacc);  // keys +16
      int r = qt * 16 + l16;
      int rc = (r < 100) ? r : 99;
      const unsigned char* mrow = mbase + (size_t)rc * 16384;
      unsigned m0 = *(const unsigned*)mrow;
      unsigned m1 = *(const unsigned*)(mrow + 16);
      if (r >= 100) { m0 = 0; m1 = 0; }
      float p[8];
#pragma unroll
      for (int rg = 0; rg < 4; ++rg) {
        float e0 = exp2f(s0[rg]);
        float e1 = exp2f(s1[rg]);
        p[rg] = ((m0 >> (rg * 8)) & 1u) ? e0 : 0.f;
        p[4 + rg] = ((m1 >> (rg * 8)) & 1u) ? e1 : 0.f;
      }
      lacc[qt] += p[0] + p[1] + p[2] + p[3] + p[4] + p[5] + p[6] + p[7];
      F8U pu;
      pu.u[0] = tpack(p[0], p[1]); pu.u[1] = tpack(p[2], p[3]);
      pu.u[2] = tpack(p[4], p[5]); pu.u[3] = tpack(p[6], p[7]);
      o[qt][0] = MFMA16(pu.f, vfB0, o[qt][0]);
      o[qt][1] = MFMA16(pu.f, vfB1, o[qt][1]);
    }
  }

  // reduce l across quads (lanes sharing l16)
#pragma unroll
  for (int qt = 0; qt < 7; ++qt) {
    lacc[qt] += __shfl_xor(lacc[qt], 16, 64);
    lacc[qt] += __shfl_xor(lacc[qt], 32, 64);
  }
  unsigned short* Op = Opartb + ((size_t)bh * 32 + chunk) * 112 * 32;
  float* lp = lpart + ((size_t)bh * 32 + chunk) * 112;
#pragma unroll
  for (int qt = 0; qt < 7; ++qt) {
#pragma unroll
    for (int rg = 0; rg < 4; ++rg) {
      int row = qt * 16 + quad * 4 + rg;
      Op[row * 32 + l16] = f2b(o[qt][0][rg]);
      Op[row * 32 + 16 + l16] = f2b(o[qt][1][rg]);
    }
    if (lane < 16) lp[qt * 16 + lane] = lacc[qt];
  }
}

// ---------- combine partials: out = sum(O) / sum(l) ----------
__global__ __launch_bounds__(256) void cross_combine(const unsigned short* __restrict__ Opartb,
                                                     const float* __restrict__ lpart,
                                                     float* __restrict__ out) {
  const int bid = blockIdx.x;
  const int bh = bid / 13, qg = bid - bh * 13;
  const int t = threadIdx.x;
  const int q = qg * 8 + (t >> 5), d = t & 31;
  if (q >= 100) return;
  const int b = bh >> 3, h = bh & 7;
  float osum = 0.f, lsum = 0.f;
#pragma unroll 4
  for (int p = 0; p < 32; ++p) {
    osum += b2f(Opartb[(((size_t)bh * 32 + p) * 112 + q) * 32 + d]);
    lsum += lpart[((size_t)bh * 32 + p) * 112 + q];
  }
  out[(size_t)(b * 100 + q) * 256 + h * 32 + d] = osum / lsum;
}

// ---------- host ----------
extern "C" void kernel_launch(void* const* d_in, const int* in_sizes, int n_in,
                              void* d_out, int out_size, void* d_ws, size_t ws_size,
                              hipStream_t stream) {
  const float* queries = (const float*)d_in[0];
  const float* pix = (const float*)d_in[1];
  const unsigned char* mask = (const unsigned char*)d_in[2];
  const float* sa_in_w = (const float*)d_in[3];
  const float* sa_in_b = (const float*)d_in[4];
  const float* sa_out_w = (const float*)d_in[5];
  const float* sa_out_b = (const float*)d_in[6];
  const float* n1g = (const float*)d_in[7];
  const float* n1b = (const float*)d_in[8];
  const float* ca_in_w = (const float*)d_in[9];
  const float* ca_in_b = (const float*)d_in[10];
  const float* ca_out_w = (const float*)d_in[11];
  const float* ca_out_b = (const float*)d_in[12];
  const float* n2g = (const float*)d_in[13];
  const float* n2b = (const float*)d_in[14];
  const float* ff_w1 = (const float*)d_in[15];
  const float* ff_b1 = (const float*)d_in[16];
  const float* ff_w2 = (const float*)d_in[17];
  const float* ff_b2 = (const float*)d_in[18];
  const float* n3g = (const float*)d_in[19];
  const float* n3b = (const float*)d_in[20];
  float* out = (float*)d_out;
  char* ws = (char*)d_ws;

  unsigned short* wb   = (unsigned short*)(ws + 134217728);    // 3145728
  float* qkvs   = (float*)(ws + 152043520);                    // 2457600
  float* sao    = (float*)(ws + 154501120);                    // 819200
  float* ptmp   = (float*)(ws + 155320320);                    // 3276800 (4 splitK partials)
  float* x1     = (float*)(ws + 158597120);                    // 819200
  float* qc     = (float*)(ws + 159416320);                    // 819200
  unsigned short* Opartb = (unsigned short*)(ws + 160235520);  // 14680064 (bf16)
  float* lpart  = (float*)(ws + 189595648);                    // 917504
  float* ca_out = (float*)(ws + 190513152);                    // 819200
  float* x2     = (float*)(ws + 191332352);                    // 819200
  float* hffn   = (float*)(ws + 192151552);                    // 6553600

  const unsigned short* wb_sain  = wb;
  const unsigned short* wb_saout = wb + 196608;
  const unsigned short* wb_caq   = wb + 262144;
  const unsigned short* wb_cakv  = wb + 327680;
  const unsigned short* wb_caout = wb + 458752;
  const unsigned short* wb_ff1   = wb + 524288;
  const unsigned short* wb_ff2   = wb + 1048576;

  cvt_weights<<<768, 256, 0, stream>>>(sa_in_w, sa_out_w, ca_in_w, ca_out_w, ff_w1, ff_w2, wb);

  // 1) self-attention block
  mfma_gemm<0, 1><<<dim3(13, 12, 1), 256, 0, stream>>>(queries, wb_sain, sa_in_b, qkvs, 800, 768, 256, 256);
  self_attn<<<1600, 256, 0, stream>>>(qkvs, sao);
  mfma_gemm<0, 1><<<dim3(13, 4, 1), 256, 0, stream>>>(sao, wb_saout, sa_out_b, ptmp, 800, 256, 256, 256);
  res_ln<<<800, 256, 0, stream>>>(ptmp, queries, n1g, n1b, x1);

  // 2) masked cross-attention block (fused KV-proj + attention)
  mfma_gemm<0, 1><<<dim3(13, 4, 1), 256, 0, stream>>>(x1, wb_caq, ca_in_b, qc, 800, 256, 256, 256);
  ca_fused<<<256, 512, 0, stream>>>(qc, wb_cakv, ca_in_b + 256, pix, mask, Opartb, lpart);
  cross_combine<<<64 * 13, 256, 0, stream>>>(Opartb, lpart, ca_out);
  mfma_gemm<0, 1><<<dim3(13, 4, 1), 256, 0, stream>>>(ca_out, wb_caout, ca_out_b, ptmp, 800, 256, 256, 256);
  res_ln<<<800, 256, 0, stream>>>(ptmp, x1, n2g, n2b, x2);

  // 3) FFN block
  mfma_gemm<1, 1><<<dim3(13, 32, 1), 256, 0, stream>>>(x2, wb_ff1, ff_b1, hffn, 800, 2048, 256, 256);
  mfma_gemm<0, 0><<<dim3(13, 4, 4), 256, 0, stream>>>(hffn, wb_ff2, nullptr, ptmp, 800, 256, 2048, 512);
  res_ln4<<<800, 256, 0, stream>>>(ptmp, ff_b2, x2, n3g, n3b, out);
}